// Round 9
// baseline (48.394 us; speedup 1.0000x reference)
//
#include <hip/hip_runtime.h>
#include <hip/hip_bf16.h>

#define NB 16     // batch
#define NN 512    // nodes
#define NF 64     // F_in == F_out
#define NE 16     // emb dim
#define NKF 192   // K*F_in
#define NNODE (NB*NN)   // 8192

typedef __hip_bfloat16 bf16;
typedef __attribute__((ext_vector_type(8))) short short8;
typedef __attribute__((ext_vector_type(4))) float f32x4;

typedef const __attribute__((address_space(1))) char gchar;
typedef __attribute__((address_space(3))) char lchar;

__device__ inline void gload16(const void* g, void* l) {
    __builtin_amdgcn_global_load_lds((gchar*)g, (lchar*)l, 16, 0, 0);
}

__device__ inline short f2bs(float f) {
    union { bf16 b; short s; } u; u.b = __float2bfloat16(f); return u.s;
}

// ---------------- k_pre: fused dinv + x(pack+transpose) + wcvt -------------
// blocks [0,2048):     dis[row] = rsqrt(sum_m relu(A[row,m]) + 1)
// blocks [2048,2176):  xg[:,0:64] = bf16(x); xT[b][f][n] = bf16(x)^T
// blocks [2176,2224):  Bt[e*64+o][kf] = bf16(Wp[e][kf][o]) via LDS transpose
__global__ __launch_bounds__(256) void k_pre(
    const float* __restrict__ A, const float* __restrict__ x,
    const float* __restrict__ Wp, float* __restrict__ dis,
    bf16* __restrict__ xg, bf16* __restrict__ xT, bf16* __restrict__ Bt) {
    __shared__ float Ts[64][66];
    int bid = blockIdx.x, tid = threadIdx.x;
    if (bid < 2048) {
        int row = bid * 4 + (tid >> 6);
        int lane = tid & 63;
        const float* a = A + (size_t)row * NN;
        float s = 0.f;
        #pragma unroll
        for (int j = 0; j < NN / 64; ++j) s += fmaxf(a[lane + 64 * j], 0.f);
        #pragma unroll
        for (int off = 32; off >= 1; off >>= 1) s += __shfl_down(s, off, 64);
        if (lane == 0) dis[row] = rsqrtf(fmaxf(s + 1.0f, 1e-6f));
    } else if (bid < 2176) {
        int node0 = (bid - 2048) * 64;
        int r = tid >> 2, f0 = (tid & 3) * 16;
        const float* xp = x + (size_t)(node0 + r) * NF + f0;
        float v[16];
        #pragma unroll
        for (int i = 0; i < 16; ++i) v[i] = xp[i];
        short8 p0, p1;
        #pragma unroll
        for (int i = 0; i < 8; ++i) { p0[i] = f2bs(v[i]); p1[i] = f2bs(v[8 + i]); }
        *(short8*)&xg[(size_t)(node0 + r) * NKF + f0] = p0;
        *(short8*)&xg[(size_t)(node0 + r) * NKF + f0 + 8] = p1;
        #pragma unroll
        for (int i = 0; i < 4; ++i)
            *(float4*)&Ts[r][f0 + i * 4] = *(const float4*)(v + i * 4);
        __syncthreads();
        int f = tid >> 2, nq0 = (tid & 3) * 16;
        int b = node0 >> 9, nloc = node0 & (NN - 1);
        bf16* xt = xT + (size_t)(b * NF + f) * NN + nloc + nq0;
        #pragma unroll
        for (int h = 0; h < 2; ++h) {
            short8 o;
            #pragma unroll
            for (int i = 0; i < 8; ++i) o[i] = f2bs(Ts[nq0 + h * 8 + i][f]);
            *(short8*)&xt[h * 8] = o;
        }
    } else {
        int q = bid - 2176;                        // 0..47
        int e = q / 3, kt = q % 3;
        int r = tid >> 2, o0 = (tid & 3) * 16;
        const float* wp = Wp + (size_t)e * (NKF * NF) + (size_t)(kt * 64 + r) * NF + o0;
        #pragma unroll
        for (int i = 0; i < 4; ++i)
            *(float4*)&Ts[r][o0 + i * 4] = *(const float4*)(wp + i * 4);
        __syncthreads();
        int o = tid >> 2, r0 = (tid & 3) * 16;
        bf16* bt = Bt + (size_t)(e * 64 + o) * NKF + kt * 64 + r0;
        #pragma unroll
        for (int h = 0; h < 2; ++h) {
            short8 w;
            #pragma unroll
            for (int i = 0; i < 8; ++i) w[i] = f2bs(Ts[r0 + h * 8 + i][o]);
            *(short8*)&bt[h * 8] = w;
        }
    }
}

// ---------------- k_ahat: Ah[b][n][m] = bf16(dn*dm*(relu(A)+I)) ------------
__global__ __launch_bounds__(256) void k_ahat(
    const float* __restrict__ A, const float* __restrict__ dis,
    bf16* __restrict__ Ah) {
    int tid = threadIdx.x;
    int row = blockIdx.x * 4 + (tid >> 6);         // global row 0..8191
    int m0 = (tid & 63) * 8;
    int b = row >> 9, n = row & (NN - 1);
    const float* db = dis + b * NN;
    float dn = db[n];
    const float* ap = A + (size_t)row * NN + m0;
    float4 a0 = *(const float4*)ap, a1 = *(const float4*)(ap + 4);
    float4 d0 = *(const float4*)(db + m0), d1 = *(const float4*)(db + m0 + 4);
    float av[8] = {a0.x, a0.y, a0.z, a0.w, a1.x, a1.y, a1.z, a1.w};
    float dm[8] = {d0.x, d0.y, d0.z, d0.w, d1.x, d1.y, d1.z, d1.w};
    short8 o;
    #pragma unroll
    for (int i = 0; i < 8; ++i) {
        float v = fmaxf(av[i], 0.f) + ((n == m0 + i) ? 1.f : 0.f);
        o[i] = f2bs(v * dn * dm[i]);
    }
    *(short8*)&Ah[(size_t)row * NN + m0] = o;
}

// ---------------- k_spmm (MFMA, k_gemm-pattern): C = Ah @ Bsrc^T -----------
// Ah rows: [n][m] bf16 (K=m); Bsrc rows: [f][m] bf16 (xT for PASS0, y1T for PASS1)
// PASS0: y1 = C -> xg[:,64:128] + y1T[b][f][n]
// PASS1: y2 = 2C - x -> xg[:,128:192]
template <int PASS>
__global__ __launch_bounds__(256) void k_spmm(
    const short* __restrict__ Ah, const short* __restrict__ Bsrc,
    const float* __restrict__ x, bf16* __restrict__ xg, bf16* __restrict__ y1T) {
    __shared__ short As[64 * 32];
    __shared__ short Xs[64 * 32];
    __shared__ float Cs[64][66];
    int tid = threadIdx.x, lane = tid & 63, w = tid >> 6;
    int n0 = blockIdx.x * 64, b = blockIdx.y;
    const short* Ab = Ah + (size_t)b * NN * NN;
    const short* Xb = Bsrc + (size_t)b * NF * NN;

    int sr = tid >> 2;                  // staging row 0..63
    int p  = tid & 3;                   // stored chunk slot
    int cA = p ^ ((sr >> 1) & 3);       // logical chunk (XOR swizzle)

    int fr = lane & 15;
    int fc = ((lane >> 4) ^ ((fr >> 1) & 3)) * 8;

    f32x4 acc[4] = {};

    for (int kt = 0; kt < 16; ++kt) {
        __syncthreads();
        gload16(Ab + (size_t)(n0 + sr) * NN + kt * 32 + cA * 8, As + tid * 8);
        gload16(Xb + (size_t)sr * NN + kt * 32 + cA * 8, Xs + tid * 8);
        __syncthreads();
        short8 afr = *(const short8*)&As[(16 * w + fr) * 32 + fc];
        #pragma unroll
        for (int j = 0; j < 4; ++j) {
            short8 bfr = *(const short8*)&Xs[(16 * j + fr) * 32 + fc];
            acc[j] = __builtin_amdgcn_mfma_f32_16x16x32_bf16(afr, bfr, acc[j], 0, 0, 0);
        }
    }

    // C[16w + 4*(lane>>4) + r][16j + (lane&15)] = acc[j][r]
    #pragma unroll
    for (int j = 0; j < 4; ++j)
        #pragma unroll
        for (int r = 0; r < 4; ++r)
            Cs[16 * w + 4 * (lane >> 4) + r][16 * j + (lane & 15)] = acc[j][r];
    __syncthreads();

    int nl = tid >> 2, f0 = (tid & 3) * 16;
    size_t node = (size_t)b * NN + n0 + nl;
    float cv[16];
    #pragma unroll
    for (int i = 0; i < 16; ++i) cv[i] = Cs[nl][f0 + i];
    if (PASS == 0) {
        short8 p0, p1;
        #pragma unroll
        for (int i = 0; i < 8; ++i) { p0[i] = f2bs(cv[i]); p1[i] = f2bs(cv[8 + i]); }
        *(short8*)&xg[node * NKF + 64 + f0] = p0;
        *(short8*)&xg[node * NKF + 64 + f0 + 8] = p1;
        int f = tid >> 2, nq0 = (tid & 3) * 16;
        bf16* yt = y1T + (size_t)(b * NF + f) * NN + n0 + nq0;
        #pragma unroll
        for (int h = 0; h < 2; ++h) {
            short8 o;
            #pragma unroll
            for (int i = 0; i < 8; ++i) o[i] = f2bs(Cs[nq0 + h * 8 + i][f]);
            *(short8*)&yt[h * 8] = o;
        }
    } else {
        const float* xp = x + node * NF + f0;
        short8 p0, p1;
        #pragma unroll
        for (int i = 0; i < 8; ++i) {
            p0[i] = f2bs(2.f * cv[i] - xp[i]);
            p1[i] = f2bs(2.f * cv[8 + i] - xp[8 + i]);
        }
        *(short8*)&xg[node * NKF + 128 + f0] = p0;
        *(short8*)&xg[node * NKF + 128 + f0 + 8] = p1;
    }
}

// ---------------- k_fused: out[n,o] = sum_e emb[n,e]*(Xg@Bt_e^T + bp[e,o]) -
// Block: 32 nodes x 64 o. A-frags (xg) hoisted once; Bt_e double-buffered.
__global__ __launch_bounds__(256) void k_fused(
    const short* __restrict__ xg, const short* __restrict__ Bt,
    const float* __restrict__ emb, const float* __restrict__ bpool,
    float* __restrict__ out) {
    __shared__ short Axs[32 * 192];        // 6 subtiles [32][32]: kk*1024 + r*32 + slot*8
    __shared__ short Bts[2][64 * 192];     // 6 subtiles [64][32]: kk*2048 + r*32 + slot*8
    int tid = threadIdx.x, lane = tid & 63, w = tid >> 6;
    int node0 = blockIdx.x * 32;

    // ---- stage xg tile (once): 3 gload16/thread, FLAT lane-linear dest
    // LDS shorts off = h*2048 + tid*8  ->  kk = h*2 + (tid>>7), r = (tid>>2)&31, slot = tid&3
    {
        int kk0 = tid >> 7;            // 0..1
        int r = (tid >> 2) & 31;
        int slot = tid & 3;
        int cA = slot ^ ((r >> 1) & 3);
        #pragma unroll
        for (int h = 0; h < 3; ++h) {
            int kk = h * 2 + kk0;
            gload16(xg + (size_t)(node0 + r) * NKF + kk * 32 + cA * 8,
                    Axs + h * 2048 + tid * 8);
        }
    }
    // ---- Bt staging map (per e: 6 gload16/thread; dest kk*2048+tid*8 = lane-linear)
    int br = tid >> 2, bslot = tid & 3;
    int bcA = bslot ^ ((br >> 1) & 3);
    #pragma unroll
    for (int kk = 0; kk < 6; ++kk)
        gload16(Bt + (size_t)(0 * 64 + br) * NKF + kk * 32 + bcA * 8,
                Bts[0] + kk * 2048 + br * 32 + bslot * 8);
    __syncthreads();   // drains all staging (vmcnt 0 before barrier)

    // ---- hoist A-fragments (constant across e)
    int fr = lane & 15, ak = lane >> 4;
    int arow = 16 * (w & 1) + fr;
    short8 afr[6];
    #pragma unroll
    for (int kk = 0; kk < 6; ++kk)
        afr[kk] = *(const short8*)&Axs[kk * 1024 + arow * 32 + ((ak ^ ((arow >> 1) & 3)) * 8)];

    float oacc[2][4] = {};
    int cur = 0;
    for (int e = 0; e < NE; ++e) {
        if (e < NE - 1) {   // stage next e while computing current
            #pragma unroll
            for (int kk = 0; kk < 6; ++kk)
                gload16(Bt + (size_t)((e + 1) * 64 + br) * NKF + kk * 32 + bcA * 8,
                        Bts[cur ^ 1] + kk * 2048 + br * 32 + bslot * 8);
        }
        f32x4 acc[2] = {};
        #pragma unroll
        for (int j = 0; j < 2; ++j) {
            int brow = 32 * (w >> 1) + 16 * j + fr;
            #pragma unroll
            for (int kk = 0; kk < 6; ++kk) {
                short8 bfr = *(const short8*)&Bts[cur][kk * 2048 + brow * 32 +
                                                       ((ak ^ ((brow >> 1) & 3)) * 8)];
                acc[j] = __builtin_amdgcn_mfma_f32_16x16x32_bf16(afr[kk], bfr, acc[j], 0, 0, 0);
            }
        }
        #pragma unroll
        for (int j = 0; j < 2; ++j) {
            int col = 32 * (w >> 1) + 16 * j + fr;    // o
            float bv = bpool[e * NF + col];
            #pragma unroll
            for (int r = 0; r < 4; ++r) {
                int nl = 16 * (w & 1) + ak * 4 + r;   // node-local
                float ev = emb[(size_t)(node0 + nl) * NE + e];
                oacc[j][r] = fmaf(ev, acc[j][r] + bv, oacc[j][r]);
            }
        }
        __syncthreads();   // next buffer staged + this buffer free for overwrite
        cur ^= 1;
    }

    #pragma unroll
    for (int j = 0; j < 2; ++j) {
        int col = 32 * (w >> 1) + 16 * j + fr;
        #pragma unroll
        for (int r = 0; r < 4; ++r) {
            int nl = 16 * (w & 1) + ak * 4 + r;
            out[(size_t)(node0 + nl) * NF + col] = oacc[j][r];
        }
    }
}

extern "C" void kernel_launch(void* const* d_in, const int* in_sizes, int n_in,
                              void* d_out, int out_size, void* d_ws, size_t ws_size,
                              hipStream_t stream) {
    const float* x   = (const float*)d_in[0];   // [16,512,64]
    const float* emb = (const float*)d_in[1];   // [16,512,16]
    const float* A   = (const float*)d_in[2];   // [16,512,512]
    const float* Wp  = (const float*)d_in[3];   // [16,3,64,64]
    const float* bp  = (const float*)d_in[4];   // [16,64]
    float* out = (float*)d_out;                 // [16,512,64]

    float* ws  = (float*)d_ws;
    float* dis = ws;                                  // 8192 f32
    bf16*  xT  = (bf16*)(ws + 8192);                  // 16*64*512 bf16 = 262144 f32-eq
    bf16*  y1T = (bf16*)(ws + 270336);                // same
    bf16*  xg  = (bf16*)(ws + 532480);                // 8192*192 bf16 = 786432 f32-eq
    bf16*  Bt  = (bf16*)(ws + 1318912);               // 1024*192 bf16 = 98304 f32-eq
    bf16*  Ah  = (bf16*)(ws + 1417216);               // 16*512*512 bf16 = 2097152 f32-eq
    // ws end: 3514368 f32 = 14.06 MB

    k_pre<<<2224, 256, 0, stream>>>(A, x, Wp, dis, xg, xT, Bt);
    k_ahat<<<2048, 256, 0, stream>>>(A, dis, Ah);
    dim3 g2(NN / 64, NB);
    k_spmm<0><<<g2, 256, 0, stream>>>((const short*)Ah, (const short*)xT, x, xg, y1T);
    k_spmm<1><<<g2, 256, 0, stream>>>((const short*)Ah, (const short*)y1T, x, xg, y1T);
    k_fused<<<NNODE / 32, 256, 0, stream>>>((const short*)xg, (const short*)Bt, emb, bp, out);
}